// Round 14
// baseline (173.827 us; speedup 1.0000x reference)
//
#include <hip/hip_runtime.h>
#include <stdint.h>

#define D 256
#define KCODES 1024
#define NROWS 65536

using int4v  = __attribute__((ext_vector_type(4))) int;
using f32x4v = __attribute__((ext_vector_type(4))) float;

__device__ __forceinline__ float rne_f(float x) { return __builtin_rintf(x); }

__device__ __forceinline__ void gl_lds16(const void* g, void* l) {
  __builtin_amdgcn_global_load_lds(
      (const __attribute__((address_space(1))) void*)g,
      (__attribute__((address_space(3))) void*)l, 16, 0, 0);
}

// 4 balanced radix-256 digits of t (|t| <= ~92), each in [-128,127] after an
// exact borrow re-encode of the +128 boundary. Value identical to the
// rounds-2..13 digit chain => bit-identical m.
__device__ __forceinline__ void dig4(float t, int* d) {
  float f0 = rne_f(t);  float t1 = __fmul_rn(__fsub_rn(t, f0), 256.0f);
  float f1 = rne_f(t1); float t2 = __fmul_rn(__fsub_rn(t1, f1), 256.0f);
  float f2 = rne_f(t2); float t3 = __fmul_rn(__fsub_rn(t2, f2), 256.0f);
  float f3 = rne_f(t3);
  int d0 = (int)f0, d1 = (int)f1, d2 = (int)f2, d3 = (int)f3;
  if (d3 == 128) { d3 = -128; ++d2; }
  if (d2 == 128) { d2 = -128; ++d1; }
  if (d1 == 128) { d1 = -128; ++d0; }
  d[0] = d0; d[1] = d1; d[2] = d2; d[3] = d3;
}

// ---------- numpy-exact pairwise sum of squares over 256 elements ----------
__device__ __forceinline__ float np_block128_sumsq(const float* __restrict__ q) {
  float r[8], v[8];
  *(float4*)(v) = *(const float4*)(q);
  *(float4*)(v + 4) = *(const float4*)(q + 4);
#pragma unroll
  for (int j = 0; j < 8; ++j) r[j] = __fmul_rn(v[j], v[j]);
  for (int i = 8; i < 128; i += 8) {
    *(float4*)(v) = *(const float4*)(q + i);
    *(float4*)(v + 4) = *(const float4*)(q + i + 4);
#pragma unroll
    for (int j = 0; j < 8; ++j) r[j] = __fadd_rn(r[j], __fmul_rn(v[j], v[j]));
  }
  float t01 = __fadd_rn(r[0], r[1]);
  float t23 = __fadd_rn(r[2], r[3]);
  float t45 = __fadd_rn(r[4], r[5]);
  float t67 = __fadd_rn(r[6], r[7]);
  return __fadd_rn(__fadd_rn(t01, t23), __fadd_rn(t45, t67));
}
__device__ __forceinline__ float np_sumsq256(const float* __restrict__ q) {
  return __fadd_rn(np_block128_sumsq(q), np_block128_sumsq(q + 128));
}

// ---- fused prep: srow (blocks 0..1023), c2 (1024..1039), cbdig (1040..1103) ----
__global__ __launch_bounds__(256) void prep_all(const float* __restrict__ z,
                                                const float* __restrict__ cb,
                                                float* __restrict__ c2,
                                                float* __restrict__ srow,
                                                char* __restrict__ cbd) {
  __shared__ float zs[64][260];
  const int bid = blockIdx.x;
  const int tid = threadIdx.x;
  if (bid < 1040) {
    const float* src; float* dst; int r0;
    if (bid < 1024) { r0 = bid * 64; src = z; dst = srow; }
    else            { r0 = (bid - 1024) * 64; src = cb; dst = c2; }
#pragma unroll
    for (int it = 0; it < 16; ++it) {
      int g = tid + it * 256, row = g >> 6, f4 = g & 63;
      *(float4*)(&zs[row][f4 * 4]) = *(const float4*)(src + (size_t)(r0 + row) * D + f4 * 4);
    }
    __syncthreads();
    if (tid < 64) dst[r0 + tid] = np_sumsq256(&zs[tid][0]);
    return;
  }
  // cbdig: codebook -> 4 int8 digit planes, k-major layout (unchanged r5-r13):
  // plane p: [nt32(0..31)][f(0..3)][c16(0..1)][kgrp(0..3)][code(0..15)][16 i8];
  // the 16B chunk covers k = f*64 + kgrp*16 .. +16 of code nt32*32 + c16*16 + code.
  int id = (bid - 1040) * 256 + tid;  // 0..16383
  int n = id >> 4, kc = id & 15;
  int f = kc >> 2, kg = kc & 3, nt = n >> 5, c = n & 31;
  const float* src = cb + (size_t)n * D + kc * 16;
  float v[16];
  *(float4*)(v) = *(const float4*)(src);
  *(float4*)(v + 4) = *(const float4*)(src + 4);
  *(float4*)(v + 8) = *(const float4*)(src + 8);
  *(float4*)(v + 12) = *(const float4*)(src + 12);
  int dg[16][4];
#pragma unroll
  for (int e = 0; e < 16; ++e) dig4(v[e] * 65536.0f, dg[e]);  // |c*2^16| <= 64
  size_t base = (size_t)nt * 8192 + f * 2048 + (c >> 4) * 1024 + kg * 256 + (c & 15) * 16;
#pragma unroll
  for (int p = 0; p < 4; ++p) {
    int4v wv;
#pragma unroll
    for (int wi = 0; wi < 4; ++wi)
      wv[wi] = (dg[wi * 4][p] & 255) | ((dg[wi * 4 + 1][p] & 255) << 8) |
               ((dg[wi * 4 + 2][p] & 255) << 16) | (dg[wi * 4 + 3][p] << 24);
    *(int4v*)(cbd + (size_t)p * (KCODES * 256) + base) = wv;
  }
}

// ---------------- main MFMA kernel (int8 16x16x64, rotated + pipelined) ----------------
#define BM 64
#define BN 16
#define NT (KCODES / BN)   // 64 tiles of 16 codes

#define MFI16(a, b, c) __builtin_amdgcn_mfma_i32_16x16x64_i8((a), (b), (c), 0, 0, 0)

// r13 structure + (1) per-wave kf rotation: wave w processes kf in order
// (w,w+1,w+2,w+3)&3, A-digits stored rotation-ordered so register indices stay
// compile-time; wave w reads its OWN staged chunk first. (2) pre-barrier
// early-LOADB of next tile's own chunk (guarded by the wave's own vmcnt(0),
// which is free: its gl_lds were issued a full tile earlier). Halves the
// post-barrier LDS burst that serialized the LDS pipe against the MFMA pipe.
__global__ __launch_bounds__(256, 4) void vq_mfma(
    const float* __restrict__ z, const float* __restrict__ cb,
    const float* __restrict__ c2g, const float* __restrict__ srowg,
    const char* __restrict__ cbd, float* __restrict__ out) {
  __shared__ alignas(16) char bbuf[2][16384];  // 4 planes x 16 codes x 256k, dbuf
  __shared__ float c2s[KCODES];
  __shared__ int bidx_s[BM];

  const int tid = threadIdx.x;
  const int lane = tid & 63;
  const int w = tid >> 6;  // wave 0..3, owns rows w*16..w*16+15
  const int r0 = blockIdx.x * BM;
  const int l15 = lane & 15, l4 = lane >> 4;

  c2s[tid] = c2g[tid];
  c2s[tid + 256] = c2g[tid + 256];
  c2s[tid + 512] = c2g[tid + 512];
  c2s[tid + 768] = c2g[tid + 768];

  float sr[4];
#pragma unroll
  for (int r = 0; r < 4; ++r) sr[r] = srowg[r0 + w * 16 + l4 * 4 + r];

  // ---- A digits, rotation-ordered: Adig[p][i] holds kf=(w+i)&3 ----
  // (16x16x64 A layout: row=l15, k = kf*64 + l4*16 + e)
  int4v Adig[4][4];
  const int kfr[4] = {w & 3, (w + 1) & 3, (w + 2) & 3, (w + 3) & 3};
  {
    const float* zrow = z + (size_t)(r0 + w * 16 + l15) * D + l4 * 16;
#pragma unroll
    for (int i = 0; i < 4; ++i) {
      const float* zr = zrow + kfr[i] * 64;
      float v[16];
      *(float4*)(v) = *(const float4*)(zr);
      *(float4*)(v + 4) = *(const float4*)(zr + 4);
      *(float4*)(v + 8) = *(const float4*)(zr + 8);
      *(float4*)(v + 12) = *(const float4*)(zr + 12);
      int dg[16][4];
#pragma unroll
      for (int e = 0; e < 16; ++e) dig4(v[e] * 16.0f, dg[e]);  // |z*16| <= ~92
#pragma unroll
      for (int p = 0; p < 4; ++p) {
        int4v wv;
#pragma unroll
        for (int wi = 0; wi < 4; ++wi)
          wv[wi] = (dg[wi * 4][p] & 255) | ((dg[wi * 4 + 1][p] & 255) << 8) |
                   ((dg[wi * 4 + 2][p] & 255) << 16) | (dg[wi * 4 + 3][p] << 24);
        Adig[p][i] = wv;
      }
    }
  }

  const char* cbd_b = cbd;
  // stage the 16-code tile ntv (4 planes x 4KB): wave w stages PHYSICAL kf-chunk w.
#define STAGE(ntv, dstbase) do { \
    const char* s_ = cbd_b + (size_t)((ntv) >> 1) * 8192 + (tid >> 6) * 2048 + \
                     ((ntv) & 1) * 1024 + (tid & 63) * 16; \
    char* d_ = (dstbase) + (tid >> 6) * 1024 + (tid & 63) * 16; \
    gl_lds16(s_,          d_); \
    gl_lds16(s_ + 262144, d_ + 4096); \
    gl_lds16(s_ + 524288, d_ + 8192); \
    gl_lds16(s_ + 786432, d_ + 12288); \
  } while (0)

  // 4 B-plane reads for physical kfrag kfv (runtime ok; wave-contig 1KB: 0 conflicts)
#define LOADB(set, basep, kfv) do { \
    const char* pk_ = (basep) + (kfv) * 1024; \
    B0##set = *(const int4v*)(pk_); \
    B1##set = *(const int4v*)(pk_ + 4096); \
    B2##set = *(const int4v*)(pk_ + 8192); \
    B3##set = *(const int4v*)(pk_ + 12288); \
  } while (0)

  // 10-MFMA cluster for rotation slot ai (compile-time) using B set `set`
#define CLUSTER(set, ai) do { \
    acc[1] = MFI16(Adig[0][ai], B1##set, acc[1]); \
    acc[3] = MFI16(Adig[0][ai], B3##set, acc[3]); \
    acc[2] = MFI16(Adig[0][ai], B2##set, acc[2]); \
    acc[1] = MFI16(Adig[1][ai], B0##set, acc[1]); \
    acc[3] = MFI16(Adig[1][ai], B2##set, acc[3]); \
    acc[2] = MFI16(Adig[1][ai], B1##set, acc[2]); \
    acc[0] = MFI16(Adig[0][ai], B0##set, acc[0]); \
    acc[3] = MFI16(Adig[2][ai], B1##set, acc[3]); \
    acc[2] = MFI16(Adig[2][ai], B0##set, acc[2]); \
    acc[3] = MFI16(Adig[3][ai], B0##set, acc[3]); \
  } while (0)

  // slot-0 variant: first write of each acc chain takes literal-zero C
#define CLUSTER0(set) do { \
    acc[1] = MFI16(Adig[0][0], B1##set, ZZ); \
    acc[3] = MFI16(Adig[0][0], B3##set, ZZ); \
    acc[2] = MFI16(Adig[0][0], B2##set, ZZ); \
    acc[1] = MFI16(Adig[1][0], B0##set, acc[1]); \
    acc[3] = MFI16(Adig[1][0], B2##set, acc[3]); \
    acc[2] = MFI16(Adig[1][0], B1##set, acc[2]); \
    acc[0] = MFI16(Adig[0][0], B0##set, ZZ); \
    acc[3] = MFI16(Adig[2][0], B1##set, acc[3]); \
    acc[2] = MFI16(Adig[2][0], B0##set, acc[2]); \
    acc[3] = MFI16(Adig[3][0], B0##set, acc[3]); \
  } while (0)

  float bd[4]; int bi[4];
#pragma unroll
  for (int r = 0; r < 4; ++r) { bd[r] = 3.4e38f; bi[r] = 0x7fffffff; }

  const int4v ZZ = {0, 0, 0, 0};
  int4v acc[4];
  int4v B0a, B1a, B2a, B3a;   // B register set a
  int4v B0b, B1b, B2b, B3b;   // B register set b

  STAGE(0, &bbuf[0][0]);
  __syncthreads();  // stage(0) complete + c2s visible
  { const char* bp0 = &bbuf[0][0] + lane * 16; LOADB(a, bp0, kfr[0]); }  // own chunk, tile 0

  for (int nt = 0; nt < NT; ++nt) {
    const char* basep = &bbuf[nt & 1][0] + lane * 16;
    if (nt + 1 < NT) STAGE(nt + 1, &bbuf[(nt + 1) & 1][0]);  // issue-before-compute

    LOADB(b, basep, kfr[1]);
    CLUSTER0(a);                 // slot 0 = kf w (zero-C first writes)
    LOADB(a, basep, kfr[2]);
    CLUSTER(b, 1);               // slot 1 = kf w+1
    LOADB(b, basep, kfr[3]);
    CLUSTER(a, 2);               // slot 2 = kf w+2
    if (nt + 1 < NT) {
      // our own 4 gl_lds for tile nt+1 were issued a full tile ago -> free wait;
      // then legally pre-read OUR OWN chunk of tile nt+1 before the barrier.
      asm volatile("s_waitcnt vmcnt(0)" ::: "memory");
      const char* nbase = &bbuf[(nt + 1) & 1][0] + lane * 16;
      LOADB(a, nbase, kfr[0]);
    }
    CLUSTER(b, 3);               // slot 3 = kf w+3

    // finalize: exact recombination; fl32(M*2^-43) == 2*fl32(M*2^-44) exactly
    // (power-of-2 scale commutes with rounding) => dist bit-identical to r2-r13.
    {
      const int kc = nt * BN + l15;
      const float c2v = c2s[kc];
#pragma unroll
      for (int r = 0; r < 4; ++r) {
        int hi32 = acc[0][r] * 256 + acc[1][r];
        double lo_d = fma((double)acc[2][r], 256.0, (double)acc[3][r]);
        float mf2 = (float)(fma((double)hi32, 65536.0, lo_d) * 0x1p-43);
        float dist = __fsub_rn(__fadd_rn(sr[r], c2v), mf2);
        if (dist < bd[r]) { bd[r] = dist; bi[r] = kc; }  // ascending kc => first-min
      }
    }
    __syncthreads();  // one barrier per tile: drains stage(nt+1), fences cur readers
  }

  // per-row argmin across the 16 code-lanes (np tie-break: lowest idx)
#pragma unroll
  for (int r = 0; r < 4; ++r) {
#pragma unroll
    for (int m = 1; m < 16; m <<= 1) {
      float od = __shfl_xor(bd[r], m);
      int oi = __shfl_xor(bi[r], m);
      if (od < bd[r] || (od == bd[r] && oi < bi[r])) { bd[r] = od; bi[r] = oi; }
    }
    if (l15 == 0) bidx_s[w * 16 + l4 * 4 + r] = bi[r];
  }
  __syncthreads();

  // epilogue: wave-per-row, lane-contiguous 1KB nontemporal stores
  {
    float* out0 = out;
    float* out1 = out + (size_t)NROWS * D;
#pragma unroll
    for (int rr = 0; rr < 16; ++rr) {
      const int row_l = w * 16 + rr;
      const int grow = r0 + row_l;
      const int kb = bidx_s[row_l];
      f32x4v c4 = *(const f32x4v*)(cb + (size_t)kb * D + lane * 4);
      f32x4v z4 = *(const f32x4v*)(z + (size_t)grow * D + lane * 4);
      f32x4v q;
      q.x = __fadd_rn(z4.x, __fsub_rn(c4.x, z4.x));
      q.y = __fadd_rn(z4.y, __fsub_rn(c4.y, z4.y));
      q.z = __fadd_rn(z4.z, __fsub_rn(c4.z, z4.z));
      q.w = __fadd_rn(z4.w, __fsub_rn(c4.w, z4.w));
      __builtin_nontemporal_store(q, (f32x4v*)(out0 + (size_t)grow * D + lane * 4));
      __builtin_nontemporal_store(c4, (f32x4v*)(out1 + (size_t)grow * D + lane * 4));
    }
  }
}

// ---------------- fallback (exact fp64 dot) if ws is too small ----------------
__global__ void c2_kernel_fb(const float* __restrict__ cb, float* __restrict__ c2) {
  int k = blockIdx.x * blockDim.x + threadIdx.x;
  if (k < KCODES) c2[k] = np_sumsq256(cb + (size_t)k * D);
}

__global__ __launch_bounds__(256) void vq_fallback(const float* __restrict__ z,
                                                   const float* __restrict__ cb,
                                                   const float* __restrict__ c2,
                                                   float* __restrict__ out) {
  __shared__ float zs[64][260];
  __shared__ float cs[64][260];
  __shared__ float srow[64];
  __shared__ int bidx[64];
  const int tid = threadIdx.x;
  const int tx = tid & 15, ty = tid >> 4;
  const int r0 = blockIdx.x * 64;
#pragma unroll
  for (int it = 0; it < 16; ++it) {
    int g = tid + it * 256, row = g >> 6, f4 = g & 63;
    *(float4*)(&zs[row][f4 * 4]) = *(const float4*)(z + (size_t)(r0 + row) * D + f4 * 4);
  }
  __syncthreads();
  if (tid < 64) srow[tid] = np_sumsq256(&zs[tid][0]);
  float bd[4]; int bi[4];
#pragma unroll
  for (int j = 0; j < 4; ++j) { bd[j] = 3.4e38f; bi[j] = 0x7fffffff; }
  for (int t = 0; t < KCODES / 64; ++t) {
    __syncthreads();
#pragma unroll
    for (int it = 0; it < 16; ++it) {
      int g = tid + it * 256, row = g >> 6, f4 = g & 63;
      *(float4*)(&cs[row][f4 * 4]) = *(const float4*)(cb + (size_t)(t * 64 + row) * D + f4 * 4);
    }
    __syncthreads();
    double acc[4][4];
#pragma unroll
    for (int j = 0; j < 4; ++j)
#pragma unroll
      for (int i = 0; i < 4; ++i) acc[j][i] = 0.0;
#pragma unroll 2
    for (int d = 0; d < D; d += 4) {
      float4 a[4], b[4];
#pragma unroll
      for (int j = 0; j < 4; ++j) a[j] = *(const float4*)(&zs[ty + 16 * j][d]);
#pragma unroll
      for (int i = 0; i < 4; ++i) b[i] = *(const float4*)(&cs[tx + 16 * i][d]);
#pragma unroll
      for (int j = 0; j < 4; ++j)
#pragma unroll
        for (int i = 0; i < 4; ++i) {
          acc[j][i] += (double)a[j].x * (double)b[i].x;
          acc[j][i] += (double)a[j].y * (double)b[i].y;
          acc[j][i] += (double)a[j].z * (double)b[i].z;
          acc[j][i] += (double)a[j].w * (double)b[i].w;
        }
    }
#pragma unroll
    for (int j = 0; j < 4; ++j) {
      const float s = srow[ty + 16 * j];
#pragma unroll
      for (int i = 0; i < 4; ++i) {
        const int k = t * 64 + tx + 16 * i;
        const float m = (float)acc[j][i];
        const float dist = __fsub_rn(__fadd_rn(s, c2[k]), __fmul_rn(2.0f, m));
        if (dist < bd[j]) { bd[j] = dist; bi[j] = k; }
      }
    }
  }
  __syncthreads();
  float* red_d = &cs[0][0];
  int* red_i = (int*)&cs[20][0];
#pragma unroll
  for (int j = 0; j < 4; ++j) {
    red_d[(ty + 16 * j) * 16 + tx] = bd[j];
    red_i[(ty + 16 * j) * 16 + tx] = bi[j];
  }
  __syncthreads();
  if (tid < 64) {
    float best = red_d[tid * 16 + 0];
    int bsti = red_i[tid * 16 + 0];
    for (int x = 1; x < 16; ++x) {
      float d2 = red_d[tid * 16 + x]; int i2 = red_i[tid * 16 + x];
      if (d2 < best || (d2 == best && i2 < bsti)) { best = d2; bsti = i2; }
    }
    bidx[tid] = bsti;
  }
  __syncthreads();
  const int wid = tid >> 6, lane = tid & 63;
  float* out0 = out;
  float* out1 = out + (size_t)NROWS * D;
  for (int r = wid; r < 64; r += 4) {
    const int gr = r0 + r;
    const int kb = bidx[r];
    float4 c4 = *(const float4*)(cb + (size_t)kb * D + lane * 4);
    float4 z4 = *(const float4*)(&zs[r][lane * 4]);
    float4 q;
    q.x = __fadd_rn(z4.x, __fsub_rn(c4.x, z4.x));
    q.y = __fadd_rn(z4.y, __fsub_rn(c4.y, z4.y));
    q.z = __fadd_rn(z4.z, __fsub_rn(c4.z, z4.z));
    q.w = __fadd_rn(z4.w, __fsub_rn(c4.w, z4.w));
    *(float4*)(out0 + (size_t)gr * D + lane * 4) = q;
    *(float4*)(out1 + (size_t)gr * D + lane * 4) = c4;
  }
}

extern "C" void kernel_launch(void* const* d_in, const int* in_sizes, int n_in,
                              void* d_out, int out_size, void* d_ws, size_t ws_size,
                              hipStream_t stream) {
  const float* z = (const float*)d_in[0];
  const float* cb = (const float*)d_in[1];
  float* out = (float*)d_out;

  const size_t c2_off = 0;                 // 4 KB
  const size_t srow_off = 4096;            // 256 KB
  const size_t cbd_off = 4096 + 262144;    // 1 MB int8 digit planes
  const size_t need = cbd_off + (size_t)4 * KCODES * 256;

  if (ws_size < need) {  // safety fallback: exact fp64 path
    float* c2 = (float*)d_ws;
    c2_kernel_fb<<<KCODES / 256, 256, 0, stream>>>(cb, c2);
    vq_fallback<<<NROWS / 64, 256, 0, stream>>>(z, cb, c2, out);
    return;
  }

  float* c2 = (float*)((char*)d_ws + c2_off);
  float* srow = (float*)((char*)d_ws + srow_off);
  char* cbd = (char*)d_ws + cbd_off;

  prep_all<<<1104, 256, 0, stream>>>(z, cb, c2, srow, cbd);
  vq_mfma<<<NROWS / BM, 256, 0, stream>>>(z, cb, c2, srow, cbd, out);
}

// Round 15
// 167.504 us; speedup vs baseline: 1.0377x; 1.0377x over previous
//
#include <hip/hip_runtime.h>
#include <stdint.h>

#define D 256
#define KCODES 1024
#define NROWS 65536

using int4v  = __attribute__((ext_vector_type(4))) int;
using f32x4v = __attribute__((ext_vector_type(4))) float;

__device__ __forceinline__ float rne_f(float x) { return __builtin_rintf(x); }

__device__ __forceinline__ void gl_lds16(const void* g, void* l) {
  __builtin_amdgcn_global_load_lds(
      (const __attribute__((address_space(1))) void*)g,
      (__attribute__((address_space(3))) void*)l, 16, 0, 0);
}

// 4 balanced radix-256 digits of t (|t| <= ~92), each in [-128,127] after an
// exact borrow re-encode of the +128 boundary. Value identical to the
// rounds-2..14 digit chain => bit-identical m.
__device__ __forceinline__ void dig4(float t, int* d) {
  float f0 = rne_f(t);  float t1 = __fmul_rn(__fsub_rn(t, f0), 256.0f);
  float f1 = rne_f(t1); float t2 = __fmul_rn(__fsub_rn(t1, f1), 256.0f);
  float f2 = rne_f(t2); float t3 = __fmul_rn(__fsub_rn(t2, f2), 256.0f);
  float f3 = rne_f(t3);
  int d0 = (int)f0, d1 = (int)f1, d2 = (int)f2, d3 = (int)f3;
  if (d3 == 128) { d3 = -128; ++d2; }
  if (d2 == 128) { d2 = -128; ++d1; }
  if (d1 == 128) { d1 = -128; ++d0; }
  d[0] = d0; d[1] = d1; d[2] = d2; d[3] = d3;
}

// ---------- numpy-exact pairwise sum of squares over 256 elements ----------
__device__ __forceinline__ float np_block128_sumsq(const float* __restrict__ q) {
  float r[8], v[8];
  *(float4*)(v) = *(const float4*)(q);
  *(float4*)(v + 4) = *(const float4*)(q + 4);
#pragma unroll
  for (int j = 0; j < 8; ++j) r[j] = __fmul_rn(v[j], v[j]);
  for (int i = 8; i < 128; i += 8) {
    *(float4*)(v) = *(const float4*)(q + i);
    *(float4*)(v + 4) = *(const float4*)(q + i + 4);
#pragma unroll
    for (int j = 0; j < 8; ++j) r[j] = __fadd_rn(r[j], __fmul_rn(v[j], v[j]));
  }
  float t01 = __fadd_rn(r[0], r[1]);
  float t23 = __fadd_rn(r[2], r[3]);
  float t45 = __fadd_rn(r[4], r[5]);
  float t67 = __fadd_rn(r[6], r[7]);
  return __fadd_rn(__fadd_rn(t01, t23), __fadd_rn(t45, t67));
}
__device__ __forceinline__ float np_sumsq256(const float* __restrict__ q) {
  return __fadd_rn(np_block128_sumsq(q), np_block128_sumsq(q + 128));
}

// ---- fused prep: srow (blocks 0..1023), c2 (1024..1039), cbdig (1040..1103) ----
__global__ __launch_bounds__(256) void prep_all(const float* __restrict__ z,
                                                const float* __restrict__ cb,
                                                float* __restrict__ c2,
                                                float* __restrict__ srow,
                                                char* __restrict__ cbd) {
  __shared__ float zs[64][260];
  const int bid = blockIdx.x;
  const int tid = threadIdx.x;
  if (bid < 1040) {
    const float* src; float* dst; int r0;
    if (bid < 1024) { r0 = bid * 64; src = z; dst = srow; }
    else            { r0 = (bid - 1024) * 64; src = cb; dst = c2; }
#pragma unroll
    for (int it = 0; it < 16; ++it) {
      int g = tid + it * 256, row = g >> 6, f4 = g & 63;
      *(float4*)(&zs[row][f4 * 4]) = *(const float4*)(src + (size_t)(r0 + row) * D + f4 * 4);
    }
    __syncthreads();
    if (tid < 64) dst[r0 + tid] = np_sumsq256(&zs[tid][0]);
    return;
  }
  // cbdig: codebook -> 4 int8 digit planes, k-major layout (unchanged r5-r14):
  // plane p: [nt32(0..31)][f(0..3)][c16(0..1)][kgrp(0..3)][code(0..15)][16 i8];
  // the 16B chunk covers k = f*64 + kgrp*16 .. +16 of code nt32*32 + c16*16 + code.
  int id = (bid - 1040) * 256 + tid;  // 0..16383
  int n = id >> 4, kc = id & 15;
  int f = kc >> 2, kg = kc & 3, nt = n >> 5, c = n & 31;
  const float* src = cb + (size_t)n * D + kc * 16;
  float v[16];
  *(float4*)(v) = *(const float4*)(src);
  *(float4*)(v + 4) = *(const float4*)(src + 4);
  *(float4*)(v + 8) = *(const float4*)(src + 8);
  *(float4*)(v + 12) = *(const float4*)(src + 12);
  int dg[16][4];
#pragma unroll
  for (int e = 0; e < 16; ++e) dig4(v[e] * 65536.0f, dg[e]);  // |c*2^16| <= 64
  size_t base = (size_t)nt * 8192 + f * 2048 + (c >> 4) * 1024 + kg * 256 + (c & 15) * 16;
#pragma unroll
  for (int p = 0; p < 4; ++p) {
    int4v wv;
#pragma unroll
    for (int wi = 0; wi < 4; ++wi)
      wv[wi] = (dg[wi * 4][p] & 255) | ((dg[wi * 4 + 1][p] & 255) << 8) |
               ((dg[wi * 4 + 2][p] & 255) << 16) | (dg[wi * 4 + 3][p] << 24);
    *(int4v*)(cbd + (size_t)p * (KCODES * 256) + base) = wv;
  }
}

// ---------------- main MFMA kernel (int8 16x16x64, dual row-frag per wave) ----------------
#define BM 128
#define BN 16
#define NT (KCODES / BN)   // 64 tiles of 16 codes

#define MFI16(a, b, c) __builtin_amdgcn_mfma_i32_16x16x64_i8((a), (b), (c), 0, 0, 0)

// r13 skeleton (LDS dbuf, 1 barrier/tile, reg-pipelined B) + each wave owns TWO
// 16-row A fragments (BM=128). Every B ds_read now feeds 20 MFMAs instead of 10:
// CU LDS-read demand halves at constant MFMA demand (the measured period was
// their serialized sum). Cost: ~232 VGPR -> (256,2) budget, 2 waves/SIMD.
__global__ __launch_bounds__(256, 2) void vq_mfma(
    const float* __restrict__ z, const float* __restrict__ cb,
    const float* __restrict__ c2g, const float* __restrict__ srowg,
    const char* __restrict__ cbd, float* __restrict__ out) {
  __shared__ alignas(16) char bbuf[2][16384];  // 4 planes x 16 codes x 256k, dbuf
  __shared__ float c2s[KCODES];
  __shared__ int bidx_s[BM];

  const int tid = threadIdx.x;
  const int lane = tid & 63;
  const int w = tid >> 6;  // wave 0..3, owns rows w*32..w*32+31 (two 16-row frags)
  const int r0 = blockIdx.x * BM;
  const int l15 = lane & 15, l4 = lane >> 4;

  c2s[tid] = c2g[tid];
  c2s[tid + 256] = c2g[tid + 256];
  c2s[tid + 512] = c2g[tid + 512];
  c2s[tid + 768] = c2g[tid + 768];

  float sr[8];
#pragma unroll
  for (int fi = 0; fi < 2; ++fi)
#pragma unroll
    for (int r = 0; r < 4; ++r)
      sr[fi * 4 + r] = srowg[r0 + w * 32 + fi * 16 + l4 * 4 + r];

  // ---- A digits, two frags: AdA rows w*32+l15, AdB rows w*32+16+l15 ----
  // (16x16x64 A layout: row=l15, k = kf*64 + l4*16 + e)
  int4v AdA[4][4], AdB[4][4];
#pragma unroll
  for (int fi = 0; fi < 2; ++fi) {
    const float* zr0 = z + (size_t)(r0 + w * 32 + fi * 16 + l15) * D + l4 * 16;
#pragma unroll
    for (int f = 0; f < 4; ++f) {
      float v[16];
      *(float4*)(v) = *(const float4*)(zr0 + f * 64);
      *(float4*)(v + 4) = *(const float4*)(zr0 + f * 64 + 4);
      *(float4*)(v + 8) = *(const float4*)(zr0 + f * 64 + 8);
      *(float4*)(v + 12) = *(const float4*)(zr0 + f * 64 + 12);
      int dg[16][4];
#pragma unroll
      for (int e = 0; e < 16; ++e) dig4(v[e] * 16.0f, dg[e]);  // |z*16| <= ~92
#pragma unroll
      for (int p = 0; p < 4; ++p) {
        int4v wv;
#pragma unroll
        for (int wi = 0; wi < 4; ++wi)
          wv[wi] = (dg[wi * 4][p] & 255) | ((dg[wi * 4 + 1][p] & 255) << 8) |
                   ((dg[wi * 4 + 2][p] & 255) << 16) | (dg[wi * 4 + 3][p] << 24);
        if (fi == 0) AdA[p][f] = wv; else AdB[p][f] = wv;
      }
    }
  }

  const char* cbd_b = cbd;
  // stage the 16-code tile ntv (4 planes x 4KB): wave w stages kf-chunk w.
#define STAGE(ntv, dstbase) do { \
    const char* s_ = cbd_b + (size_t)((ntv) >> 1) * 8192 + (tid >> 6) * 2048 + \
                     ((ntv) & 1) * 1024 + (tid & 63) * 16; \
    char* d_ = (dstbase) + (tid >> 6) * 1024 + (tid & 63) * 16; \
    gl_lds16(s_,          d_); \
    gl_lds16(s_ + 262144, d_ + 4096); \
    gl_lds16(s_ + 524288, d_ + 8192); \
    gl_lds16(s_ + 786432, d_ + 12288); \
  } while (0)

  // 4 B-plane reads for kfrag kf into a named set (wave-contiguous 1KB: 0 conflicts)
#define LOADB(set, basep, kf) do { \
    const char* pk_ = (basep) + (kf) * 1024; \
    B0##set = *(const int4v*)(pk_); \
    B1##set = *(const int4v*)(pk_ + 4096); \
    B2##set = *(const int4v*)(pk_ + 8192); \
    B3##set = *(const int4v*)(pk_ + 12288); \
  } while (0)

  // 20-MFMA dual-frag cluster for kfrag kf with B set `set` (A/B interleaved:
  // same-acc distance >= 2; integer accumulation => order-free, value identical)
#define CLUSTER2(set, kf) do { \
    accA[1] = MFI16(AdA[0][kf], B1##set, accA[1]); \
    accB[1] = MFI16(AdB[0][kf], B1##set, accB[1]); \
    accA[3] = MFI16(AdA[0][kf], B3##set, accA[3]); \
    accB[3] = MFI16(AdB[0][kf], B3##set, accB[3]); \
    accA[2] = MFI16(AdA[0][kf], B2##set, accA[2]); \
    accB[2] = MFI16(AdB[0][kf], B2##set, accB[2]); \
    accA[1] = MFI16(AdA[1][kf], B0##set, accA[1]); \
    accB[1] = MFI16(AdB[1][kf], B0##set, accB[1]); \
    accA[3] = MFI16(AdA[1][kf], B2##set, accA[3]); \
    accB[3] = MFI16(AdB[1][kf], B2##set, accB[3]); \
    accA[2] = MFI16(AdA[1][kf], B1##set, accA[2]); \
    accB[2] = MFI16(AdB[1][kf], B1##set, accB[2]); \
    accA[0] = MFI16(AdA[0][kf], B0##set, accA[0]); \
    accB[0] = MFI16(AdB[0][kf], B0##set, accB[0]); \
    accA[3] = MFI16(AdA[2][kf], B1##set, accA[3]); \
    accB[3] = MFI16(AdB[2][kf], B1##set, accB[3]); \
    accA[2] = MFI16(AdA[2][kf], B0##set, accA[2]); \
    accB[2] = MFI16(AdB[2][kf], B0##set, accB[2]); \
    accA[3] = MFI16(AdA[3][kf], B0##set, accA[3]); \
    accB[3] = MFI16(AdB[3][kf], B0##set, accB[3]); \
  } while (0)

  // kf=0 variant: first write of each acc chain takes literal-zero C
#define CLUSTER20(set) do { \
    accA[1] = MFI16(AdA[0][0], B1##set, ZZ); \
    accB[1] = MFI16(AdB[0][0], B1##set, ZZ); \
    accA[3] = MFI16(AdA[0][0], B3##set, ZZ); \
    accB[3] = MFI16(AdB[0][0], B3##set, ZZ); \
    accA[2] = MFI16(AdA[0][0], B2##set, ZZ); \
    accB[2] = MFI16(AdB[0][0], B2##set, ZZ); \
    accA[1] = MFI16(AdA[1][0], B0##set, accA[1]); \
    accB[1] = MFI16(AdB[1][0], B0##set, accB[1]); \
    accA[3] = MFI16(AdA[1][0], B2##set, accA[3]); \
    accB[3] = MFI16(AdB[1][0], B2##set, accB[3]); \
    accA[2] = MFI16(AdA[1][0], B1##set, accA[2]); \
    accB[2] = MFI16(AdB[1][0], B1##set, accB[2]); \
    accA[0] = MFI16(AdA[0][0], B0##set, ZZ); \
    accB[0] = MFI16(AdB[0][0], B0##set, ZZ); \
    accA[3] = MFI16(AdA[2][0], B1##set, accA[3]); \
    accB[3] = MFI16(AdB[2][0], B1##set, accB[3]); \
    accA[2] = MFI16(AdA[2][0], B0##set, accA[2]); \
    accB[2] = MFI16(AdB[2][0], B0##set, accB[2]); \
    accA[3] = MFI16(AdA[3][0], B0##set, accA[3]); \
    accB[3] = MFI16(AdB[3][0], B0##set, accB[3]); \
  } while (0)

  float bd[8]; int bi[8];
#pragma unroll
  for (int r = 0; r < 8; ++r) { bd[r] = 3.4e38f; bi[r] = 0x7fffffff; }

  const int4v ZZ = {0, 0, 0, 0};
  int4v accA[4], accB[4];
  int4v B0a, B1a, B2a, B3a;   // B register set a
  int4v B0b, B1b, B2b, B3b;   // B register set b

  STAGE(0, &bbuf[0][0]);
  __syncthreads();  // stage(0) complete + c2s visible

  for (int nt = 0; nt < NT; ++nt) {
    const char* basep = &bbuf[nt & 1][0] + lane * 16;
    if (nt + 1 < NT) STAGE(nt + 1, &bbuf[(nt + 1) & 1][0]);  // issue-before-compute

    LOADB(a, basep, 0);     // kf0 -> set a
    LOADB(b, basep, 1);     // prefetch kf1 -> set b (in flight under kf0 MFMAs)
    CLUSTER20(a);           // kf0 (zero-C first writes)
    LOADB(a, basep, 2);     // prefetch kf2 -> set a
    CLUSTER2(b, 1);         // kf1
    LOADB(b, basep, 3);     // prefetch kf3 -> set b
    CLUSTER2(a, 2);         // kf2
    CLUSTER2(b, 3);         // kf3

    // finalize both frags: exact recombination; fl32(M*2^-43) == 2*fl32(M*2^-44)
    // exactly (power-of-2 scale commutes with rounding) => dist bit-identical.
    {
      const int kc = nt * BN + l15;
      const float c2v = c2s[kc];
#pragma unroll
      for (int r = 0; r < 4; ++r) {
        int hi32 = accA[0][r] * 256 + accA[1][r];
        double lo_d = fma((double)accA[2][r], 256.0, (double)accA[3][r]);
        float mf2 = (float)(fma((double)hi32, 65536.0, lo_d) * 0x1p-43);
        float dist = __fsub_rn(__fadd_rn(sr[r], c2v), mf2);
        if (dist < bd[r]) { bd[r] = dist; bi[r] = kc; }
      }
#pragma unroll
      for (int r = 0; r < 4; ++r) {
        int hi32 = accB[0][r] * 256 + accB[1][r];
        double lo_d = fma((double)accB[2][r], 256.0, (double)accB[3][r]);
        float mf2 = (float)(fma((double)hi32, 65536.0, lo_d) * 0x1p-43);
        float dist = __fsub_rn(__fadd_rn(sr[4 + r], c2v), mf2);
        if (dist < bd[4 + r]) { bd[4 + r] = dist; bi[4 + r] = kc; }
      }
    }
    __syncthreads();  // one barrier per tile: drains stage(nt+1), fences cur readers
  }

  // per-row argmin across the 16 code-lanes (np tie-break: lowest idx)
#pragma unroll
  for (int r = 0; r < 8; ++r) {
#pragma unroll
    for (int m = 1; m < 16; m <<= 1) {
      float od = __shfl_xor(bd[r], m);
      int oi = __shfl_xor(bi[r], m);
      if (od < bd[r] || (od == bd[r] && oi < bi[r])) { bd[r] = od; bi[r] = oi; }
    }
    if (l15 == 0) bidx_s[w * 32 + (r >> 2) * 16 + l4 * 4 + (r & 3)] = bi[r];
  }
  __syncthreads();

  // epilogue: wave-per-row, lane-contiguous 1KB nontemporal stores
  {
    float* out0 = out;
    float* out1 = out + (size_t)NROWS * D;
#pragma unroll
    for (int rr = 0; rr < 32; ++rr) {
      const int row_l = w * 32 + rr;
      const int grow = r0 + row_l;
      const int kb = bidx_s[row_l];
      f32x4v c4 = *(const f32x4v*)(cb + (size_t)kb * D + lane * 4);
      f32x4v z4 = *(const f32x4v*)(z + (size_t)grow * D + lane * 4);
      f32x4v q;
      q.x = __fadd_rn(z4.x, __fsub_rn(c4.x, z4.x));
      q.y = __fadd_rn(z4.y, __fsub_rn(c4.y, z4.y));
      q.z = __fadd_rn(z4.z, __fsub_rn(c4.z, z4.z));
      q.w = __fadd_rn(z4.w, __fsub_rn(c4.w, z4.w));
      __builtin_nontemporal_store(q, (f32x4v*)(out0 + (size_t)grow * D + lane * 4));
      __builtin_nontemporal_store(c4, (f32x4v*)(out1 + (size_t)grow * D + lane * 4));
    }
  }
}

// ---------------- fallback (exact fp64 dot) if ws is too small ----------------
__global__ void c2_kernel_fb(const float* __restrict__ cb, float* __restrict__ c2) {
  int k = blockIdx.x * blockDim.x + threadIdx.x;
  if (k < KCODES) c2[k] = np_sumsq256(cb + (size_t)k * D);
}

__global__ __launch_bounds__(256) void vq_fallback(const float* __restrict__ z,
                                                   const float* __restrict__ cb,
                                                   const float* __restrict__ c2,
                                                   float* __restrict__ out) {
  __shared__ float zs[64][260];
  __shared__ float cs[64][260];
  __shared__ float srow[64];
  __shared__ int bidx[64];
  const int tid = threadIdx.x;
  const int tx = tid & 15, ty = tid >> 4;
  const int r0 = blockIdx.x * 64;
#pragma unroll
  for (int it = 0; it < 16; ++it) {
    int g = tid + it * 256, row = g >> 6, f4 = g & 63;
    *(float4*)(&zs[row][f4 * 4]) = *(const float4*)(z + (size_t)(r0 + row) * D + f4 * 4);
  }
  __syncthreads();
  if (tid < 64) srow[tid] = np_sumsq256(&zs[tid][0]);
  float bd[4]; int bi[4];
#pragma unroll
  for (int j = 0; j < 4; ++j) { bd[j] = 3.4e38f; bi[j] = 0x7fffffff; }
  for (int t = 0; t < KCODES / 64; ++t) {
    __syncthreads();
#pragma unroll
    for (int it = 0; it < 16; ++it) {
      int g = tid + it * 256, row = g >> 6, f4 = g & 63;
      *(float4*)(&cs[row][f4 * 4]) = *(const float4*)(cb + (size_t)(t * 64 + row) * D + f4 * 4);
    }
    __syncthreads();
    double acc[4][4];
#pragma unroll
    for (int j = 0; j < 4; ++j)
#pragma unroll
      for (int i = 0; i < 4; ++i) acc[j][i] = 0.0;
#pragma unroll 2
    for (int d = 0; d < D; d += 4) {
      float4 a[4], b[4];
#pragma unroll
      for (int j = 0; j < 4; ++j) a[j] = *(const float4*)(&zs[ty + 16 * j][d]);
#pragma unroll
      for (int i = 0; i < 4; ++i) b[i] = *(const float4*)(&cs[tx + 16 * i][d]);
#pragma unroll
      for (int j = 0; j < 4; ++j)
#pragma unroll
        for (int i = 0; i < 4; ++i) {
          acc[j][i] += (double)a[j].x * (double)b[i].x;
          acc[j][i] += (double)a[j].y * (double)b[i].y;
          acc[j][i] += (double)a[j].z * (double)b[i].z;
          acc[j][i] += (double)a[j].w * (double)b[i].w;
        }
    }
#pragma unroll
    for (int j = 0; j < 4; ++j) {
      const float s = srow[ty + 16 * j];
#pragma unroll
      for (int i = 0; i < 4; ++i) {
        const int k = t * 64 + tx + 16 * i;
        const float m = (float)acc[j][i];
        const float dist = __fsub_rn(__fadd_rn(s, c2[k]), __fmul_rn(2.0f, m));
        if (dist < bd[j]) { bd[j] = dist; bi[j] = k; }
      }
    }
  }
  __syncthreads();
  float* red_d = &cs[0][0];
  int* red_i = (int*)&cs[20][0];
#pragma unroll
  for (int j = 0; j < 4; ++j) {
    red_d[(ty + 16 * j) * 16 + tx] = bd[j];
    red_i[(ty + 16 * j) * 16 + tx] = bi[j];
  }
  __syncthreads();
  if (tid < 64) {
    float best = red_d[tid * 16 + 0];
    int bsti = red_i[tid * 16 + 0];
    for (int x = 1; x < 16; ++x) {
      float d2 = red_d[tid * 16 + x]; int i2 = red_i[tid * 16 + x];
      if (d2 < best || (d2 == best && i2 < bsti)) { best = d2; bsti = i2; }
    }
    bidx[tid] = bsti;
  }
  __syncthreads();
  const int wid = tid >> 6, lane = tid & 63;
  float* out0 = out;
  float* out1 = out + (size_t)NROWS * D;
  for (int r = wid; r < 64; r += 4) {
    const int gr = r0 + r;
    const int kb = bidx[r];
    float4 c4 = *(const float4*)(cb + (size_t)kb * D + lane * 4);
    float4 z4 = *(const float4*)(&zs[r][lane * 4]);
    float4 q;
    q.x = __fadd_rn(z4.x, __fsub_rn(c4.x, z4.x));
    q.y = __fadd_rn(z4.y, __fsub_rn(c4.y, z4.y));
    q.z = __fadd_rn(z4.z, __fsub_rn(c4.z, z4.z));
    q.w = __fadd_rn(z4.w, __fsub_rn(c4.w, z4.w));
    *(float4*)(out0 + (size_t)gr * D + lane * 4) = q;
    *(float4*)(out1 + (size_t)gr * D + lane * 4) = c4;
  }
}

extern "C" void kernel_launch(void* const* d_in, const int* in_sizes, int n_in,
                              void* d_out, int out_size, void* d_ws, size_t ws_size,
                              hipStream_t stream) {
  const float* z = (const float*)d_in[0];
  const float* cb = (const float*)d_in[1];
  float* out = (float*)d_out;

  const size_t c2_off = 0;                 // 4 KB
  const size_t srow_off = 4096;            // 256 KB
  const size_t cbd_off = 4096 + 262144;    // 1 MB int8 digit planes
  const size_t need = cbd_off + (size_t)4 * KCODES * 256;

  if (ws_size < need) {  // safety fallback: exact fp64 path
    float* c2 = (float*)d_ws;
    c2_kernel_fb<<<KCODES / 256, 256, 0, stream>>>(cb, c2);
    vq_fallback<<<NROWS / 64, 256, 0, stream>>>(z, cb, c2, out);
    return;
  }

  float* c2 = (float*)((char*)d_ws + c2_off);
  float* srow = (float*)((char*)d_ws + srow_off);
  char* cbd = (char*)d_ws + cbd_off;

  prep_all<<<1104, 256, 0, stream>>>(z, cb, c2, srow, cbd);
  vq_mfma<<<NROWS / BM, 256, 0, stream>>>(z, cb, c2, srow, cbd, out);
}